// Round 11
// baseline (377.395 us; speedup 1.0000x reference)
//
#include <hip/hip_runtime.h>
#include <math.h>

// x: [B=8, C=1, D=3, H=1536, W=1536] fp32
// out = (x - maxpool3x3x3(x) + 1e-5 > 0) ? x : 0 (pool broadcast over depth).
// Separable: m = depth-max over planes (LDS), mp = 3x3 spatial max of m.
//
// R10: R9's batched-load/register-x/batched-store kernel + XCD-chunked block
// assignment (ONE BATCH PER XCD).
// Post-mortem R9: structure win (~136->~127us) but still ~45% of achievable
// mixed BW. Remaining theory: DRAM row-buffer scatter. Plane stride (9*2^20)
// and batch stride (27*2^20) have zero low bits -> same channel+bank,
// different DRAM rows. ~768 co-resident blocks x 6 streams = thousands of
// scattered 48KB islands -> per-bank queues hold ~1 request per row ->
// activate per access. Fix: dispatch round-robins bid%8 across XCDs (T1);
// swz=(bid&7)*256+(bid>>3) gives XCD k batch k with strips ascending, so each
// XCD sweeps one batch as a contiguous ~576-row band (48 long fronts total
// instead of a 256-tooth comb x 3 batches), and strip halos become L2-local.

#define Hh   1536
#define Ww   1536
#define EPSf 1e-5f
#define TH   6                  // output rows per block
#define NRr  (TH + 2)           // LDS rows (with vertical halo) = 8
#define ROWP 1544               // [0..2] dead, [3]=left pad, [4..1539]=cols, [1540]=right pad
#define NSTRIP (Hh / TH)        // 256 strips
#define NTHR 384                // one f4-column per thread

typedef float f4 __attribute__((ext_vector_type(4)));

__global__ __launch_bounds__(NTHR, 3) void nms3d_kernel(const float* __restrict__ x,
                                                        float* __restrict__ out) {
    __shared__ float sm[NRr][ROWP];     // depth-max rows h0-1 .. h0+TH, 49.4 KB

    const int t = threadIdx.x;
    // XCD-chunked assignment: XCD (bid%8) gets contiguous task range.
    // swz in [0,2048) bijective; b = swz>>8 (batch == XCD), s = swz&255.
    const int swz = (blockIdx.x & 7) * 256 + (blockIdx.x >> 3);
    const int s = swz & 255;            // strip: consecutive per-XCD blocks = adjacent strips
    const int b = swz >> 8;             // batch (one per XCD)

    const int h0 = s * TH;
    const size_t plane = (size_t)Hh * Ww;
    const float* xb = x + (size_t)b * 3 * plane;
    float*       ob = out + (size_t)b * 3 * plane;

    const float NI = -INFINITY, PIF = INFINITY;

    // image-edge pads (cols -1 and W) = -inf, once
    if (t < 2 * NRr) {
        const int r = t >> 1;
        sm[r][(t & 1) ? 1540 : 3] = NI;
    }

    // ---------------- Phase 1: 24 loads up front, depth-max -> LDS ----------
    // Per row r (image row h0-1+r, clamped), block reads a full 6 KB row per
    // plane: 384 thr x 16 B contiguous. All loads issued before any consumer.
    f4 xv[NRr][3];
#pragma unroll
    for (int r = 0; r < NRr; ++r) {
        const int h  = h0 - 1 + r;
        const int hc = h < 0 ? 0 : (h > Hh - 1 ? Hh - 1 : h);
        const float* p = xb + (size_t)hc * Ww + 4 * t;
        xv[r][0] = *(const f4*)(p);
        xv[r][1] = *(const f4*)(p + plane);
        xv[r][2] = *(const f4*)(p + 2 * plane);
    }
    // Fence: keep all 24 loads issued before consumers (consumers are
    // data-dependent LDS stores -> cannot be hoisted above the loads).
    __builtin_amdgcn_sched_barrier(0);

#pragma unroll
    for (int r = 0; r < NRr; ++r) {
        const int h = h0 - 1 + r;
        const float bound = ((unsigned)h < (unsigned)Hh) ? PIF : NI;
        f4 m;
        m.x = fminf(fmaxf(xv[r][0].x, fmaxf(xv[r][1].x, xv[r][2].x)), bound);
        m.y = fminf(fmaxf(xv[r][0].y, fmaxf(xv[r][1].y, xv[r][2].y)), bound);
        m.z = fminf(fmaxf(xv[r][0].z, fmaxf(xv[r][1].z, xv[r][2].z)), bound);
        m.w = fminf(fmaxf(xv[r][0].w, fmaxf(xv[r][1].w, xv[r][2].w)), bound);
        *(f4*)&sm[r][4 + 4 * t] = m;    // conflict-free: lane stride 16B
    }
    __syncthreads();

    // ---------------- Phase 2: mp from LDS, mask register-x, batched stores -
    f4 mpv[TH];
#pragma unroll
    for (int rr = 0; rr < TH; ++rr) {
        // window cols 4t-1 .. 4t+4 over sm rows rr..rr+2, via aligned f4s
        float l = NI, w0v = NI, w1v = NI, w2v = NI, w3v = NI, rt = NI;
#pragma unroll
        for (int dr = 0; dr < 3; ++dr) {
            const float* row = &sm[rr + dr][0];
            const f4 q0 = *(const f4*)&row[4 * t];       // .w = col 4t-1
            const f4 q1 = *(const f4*)&row[4 * t + 4];   // cols 4t..4t+3
            const f4 q2 = *(const f4*)&row[4 * t + 8];   // .x = col 4t+4
            l   = fmaxf(l,   q0.w);
            w0v = fmaxf(w0v, q1.x);
            w1v = fmaxf(w1v, q1.y);
            w2v = fmaxf(w2v, q1.z);
            w3v = fmaxf(w3v, q1.w);
            rt  = fmaxf(rt,  q2.x);
        }
        mpv[rr].x = fmaxf(l,   fmaxf(w0v, w1v));
        mpv[rr].y = fmaxf(w0v, fmaxf(w1v, w2v));
        mpv[rr].z = fmaxf(w1v, fmaxf(w2v, w3v));
        mpv[rr].w = fmaxf(w2v, fmaxf(w3v, rt));
    }

    // All 18 stores at the end, plane-major: per plane a block emits 6
    // consecutive full rows (36 KB sequential). No load ever waits on these.
#pragma unroll
    for (int d = 0; d < 3; ++d) {
        float* pd = ob + (size_t)d * plane + (size_t)h0 * Ww + 4 * t;
#pragma unroll
        for (int rr = 0; rr < TH; ++rr) {
            const f4 a = xv[rr + 1][d];          // x held in registers since phase 1
            const f4 mp = mpv[rr];
            f4 o;
            o.x = ((a.x - mp.x) + EPSf > 0.0f) ? a.x : 0.0f;
            o.y = ((a.y - mp.y) + EPSf > 0.0f) ? a.y : 0.0f;
            o.z = ((a.z - mp.z) + EPSf > 0.0f) ? a.z : 0.0f;
            o.w = ((a.w - mp.w) + EPSf > 0.0f) ? a.w : 0.0f;
            *(f4*)(pd + (size_t)rr * Ww) = o;
        }
    }
}

extern "C" void kernel_launch(void* const* d_in, const int* in_sizes, int n_in,
                              void* d_out, int out_size, void* d_ws, size_t ws_size,
                              hipStream_t stream) {
    const float* x = (const float*)d_in[0];
    float* out = (float*)d_out;
    const int grid = 8 * NSTRIP;   // 2048 blocks, XCD-chunked via in-kernel swizzle
    nms3d_kernel<<<dim3(grid), dim3(NTHR), 0, stream>>>(x, out);
}